// Round 1
// baseline (198.444 us; speedup 1.0000x reference)
//
#include <hip/hip_runtime.h>

// Problem constants
// B=4, HG=WG=32 -> 1024 tokens/batch, 4096 total; D=768, NH=12, HD=64, K=7 (49 neighbors)

typedef __bf16 bf16x8 __attribute__((ext_vector_type(8)));
typedef float f32x4 __attribute__((ext_vector_type(4)));

__device__ __forceinline__ unsigned short f2bf(float f) {
  unsigned u = __float_as_uint(f);
  u += 0x7fffu + ((u >> 16) & 1u);   // RNE
  return (unsigned short)(u >> 16);
}
__device__ __forceinline__ float bflo(unsigned u) { return __uint_as_float(u << 16); }
__device__ __forceinline__ float bfhi(unsigned u) { return __uint_as_float(u & 0xffff0000u); }

template <typename T>
__device__ __forceinline__ void gld_lds16(const T* g, T* l) {
  __builtin_amdgcn_global_load_lds((const __attribute__((address_space(1))) void*)g,
                                   (__attribute__((address_space(3))) void*)l, 16, 0, 0);
}

// ---------------- fp32 -> bf16 conversion of x, qkv_w, proj_w ----------------
__global__ void cvt_kernel(const float* __restrict__ x, const float* __restrict__ w1,
                           const float* __restrict__ w2, unsigned short* __restrict__ xo,
                           unsigned short* __restrict__ w1o, unsigned short* __restrict__ w2o) {
  const int n1 = 4096 * 768 / 4;   // 786432 float4s
  const int n2 = 2304 * 768 / 4;   // 442368
  const int n3 = 768 * 768 / 4;    // 147456
  int i = blockIdx.x * 256 + threadIdx.x;
  float4 v;
  unsigned short* dst;
  int o;
  if (i < n1) {
    o = i; v = ((const float4*)x)[o]; dst = xo;
  } else if (i < n1 + n2) {
    o = i - n1; v = ((const float4*)w1)[o]; dst = w1o;
  } else if (i < n1 + n2 + n3) {
    o = i - n1 - n2; v = ((const float4*)w2)[o]; dst = w2o;
  } else {
    return;
  }
  ushort4 r;
  r.x = f2bf(v.x); r.y = f2bf(v.y); r.z = f2bf(v.z); r.w = f2bf(v.w);
  ((ushort4*)dst)[o] = r;
}

// ---------------- bf16 GEMM, C = A * B^T + bias ----------------
// A: [M][K] bf16 row-major.  Bm: [N][K] bf16 row-major (i.e. B^T layout).
// MODE 0: write bf16 to qkv_t layout [(s*12+h)*4096 + m][64] (s=col/768, h=(col%768)/64, d=col%64)
// MODE 1: write fp32 to of32[m*N + n]
template <int MODE>
__global__ __launch_bounds__(256) void gemm_bt(const unsigned short* __restrict__ A,
                                               const unsigned short* __restrict__ Bm,
                                               const float* __restrict__ bias,
                                               unsigned short* __restrict__ obf,
                                               float* __restrict__ of32,
                                               int M, int N, int Kd) {
  __shared__ __align__(16) unsigned short sA[128 * 32];
  __shared__ __align__(16) unsigned short sB[128 * 32];
  const int tid = threadIdx.x;
  const int lane = tid & 63;
  const int wv = tid >> 6;
  const int m0 = blockIdx.y * 128, n0 = blockIdx.x * 128;
  const int wrow = (wv >> 1) * 64, wcol = (wv & 1) * 64;
  const int lr = lane & 15, lq = lane >> 4;

  f32x4 acc[4][4] = {};

  const unsigned short* gA = A + (size_t)(m0 + (tid >> 2)) * Kd + (tid & 3) * 8;
  const unsigned short* gB = Bm + (size_t)(n0 + (tid >> 2)) * Kd + (tid & 3) * 8;

  for (int k0 = 0; k0 < Kd; k0 += 32) {
    gld_lds16(gA + k0, sA + tid * 8);
    gld_lds16(gA + (size_t)64 * Kd + k0, sA + 2048 + tid * 8);
    gld_lds16(gB + k0, sB + tid * 8);
    gld_lds16(gB + (size_t)64 * Kd + k0, sB + 2048 + tid * 8);
    __syncthreads();

    bf16x8 af[4], bfr[4];
#pragma unroll
    for (int t = 0; t < 4; ++t) {
      af[t] = *(const bf16x8*)(sA + (wrow + t * 16 + lr) * 32 + lq * 8);
      bfr[t] = *(const bf16x8*)(sB + (wcol + t * 16 + lr) * 32 + lq * 8);
    }
#pragma unroll
    for (int im = 0; im < 4; ++im)
#pragma unroll
      for (int in = 0; in < 4; ++in)
        acc[im][in] = __builtin_amdgcn_mfma_f32_16x16x32_bf16(af[im], bfr[in], acc[im][in], 0, 0, 0);
    __syncthreads();
  }

#pragma unroll
  for (int im = 0; im < 4; ++im) {
#pragma unroll
    for (int in = 0; in < 4; ++in) {
      int gn = n0 + wcol + in * 16 + lr;
      float bsv = bias[gn];
#pragma unroll
      for (int r = 0; r < 4; ++r) {
        int gm = m0 + wrow + im * 16 + lq * 4 + r;
        float val = acc[im][in][r] + bsv;
        if (MODE == 0) {
          int sidx = gn / 768;
          int rem = gn - sidx * 768;
          int hh = rem >> 6;
          int dd = gn & 63;
          obf[((size_t)(sidx * 12 + hh) * 4096 + gm) * 64 + dd] = f2bf(val);
        } else {
          of32[(size_t)gm * N + gn] = val;
        }
      }
    }
  }
}

// ---------------- neighborhood attention ----------------
// qkv_t: [3][12][4096][64] bf16.  aout: [4096][768] bf16.
// One block per (head, row i, batch). LDS: Q[32][64]; K,V as [c*7+wr][64] with
// 16B-chunk XOR swizzle (chunk ^= row&7) so 49-window reads and lane=dim reads
// are both ~conflict-free.
__global__ __launch_bounds__(256) void natten_kernel(const unsigned short* __restrict__ qkvt,
                                                     unsigned short* __restrict__ aout) {
  __shared__ __align__(16) unsigned short sQ[32 * 64];
  __shared__ __align__(16) unsigned short sK[224 * 64];
  __shared__ __align__(16) unsigned short sV[224 * 64];
  const int h = blockIdx.x, iq = blockIdx.y, b = blockIdx.z;
  const int tid = threadIdx.x, lane = tid & 63, wv = tid >> 6;
  int si = iq - 3; si = si < 0 ? 0 : si; si = si > 25 ? 25 : si;
  const int gb = b * 1024;

  // stage Q (4 KB contiguous)
  {
    const uint4* qs = (const uint4*)(qkvt + ((size_t)h * 4096 + gb + iq * 32) * 64);
    ((uint4*)sQ)[tid] = qs[tid];
  }
  // stage K/V (7 iters x 256 threads x 16B each)
  {
    const unsigned short* ks = qkvt + ((size_t)(12 + h) * 4096 + gb) * 64;
    const unsigned short* vs = qkvt + ((size_t)(24 + h) * 4096 + gb) * 64;
#pragma unroll
    for (int it = 0; it < 7; ++it) {
      int f = it * 256 + tid;
      int ldsr = f >> 3, ch = f & 7;
      int c = ldsr / 7;
      int wr2 = ldsr - c * 7;
      int tok = (si + wr2) * 32 + c;
      int dsto = ldsr * 64 + ((ch ^ (ldsr & 7)) << 3);
      *(uint4*)(sK + dsto) = *(const uint4*)(ks + tok * 64 + ch * 8);
      *(uint4*)(sV + dsto) = *(const uint4*)(vs + tok * 64 + ch * 8);
    }
  }
  __syncthreads();

  const int wrl = lane / 7;                    // window row for this lane (lane<49)
  const int wcl = lane - wrl * 7;              // window col offset
  const int m_l = wcl * 7 + wrl;               // distinct 0..48 for lane<49
  const bool act = lane < 49;
  const int d_off = ((lane >> 3) << 4) | ((lane & 7) << 1);  // byte offset of dim=lane in a row (pre-swizzle)

  for (int jj = 0; jj < 8; ++jj) {
    const int jq = wv * 8 + jj;
    int sj = jq - 3; sj = sj < 0 ? 0 : sj; sj = sj > 25 ? 25 : sj;
    int ldsr = sj * 7 + m_l;
    if (!act) ldsr = 0;
    const int g = ldsr & 7;

    // scores: lane = neighbor, 64-dim dot from LDS
    float s = 0.f;
    const uint4* qrow = (const uint4*)(sQ + jq * 64);
#pragma unroll
    for (int ch = 0; ch < 8; ++ch) {
      uint4 kv = *(const uint4*)(sK + ldsr * 64 + ((ch ^ g) << 3));
      uint4 qv = qrow[ch];
      s = fmaf(bflo(kv.x), bflo(qv.x), s);
      s = fmaf(bfhi(kv.x), bfhi(qv.x), s);
      s = fmaf(bflo(kv.y), bflo(qv.y), s);
      s = fmaf(bfhi(kv.y), bfhi(qv.y), s);
      s = fmaf(bflo(kv.z), bflo(qv.z), s);
      s = fmaf(bfhi(kv.z), bfhi(qv.z), s);
      s = fmaf(bflo(kv.w), bflo(qv.w), s);
      s = fmaf(bfhi(kv.w), bfhi(qv.w), s);
    }
    s *= 0.125f;  // HD^-0.5

    // softmax across the 49 neighbor lanes (64-lane butterfly)
    float sm = act ? s : -1e30f;
#pragma unroll
    for (int off = 32; off >= 1; off >>= 1) sm = fmaxf(sm, __shfl_xor(sm, off, 64));
    float p = act ? __expf(s - sm) : 0.f;
    float ps = p;
#pragma unroll
    for (int off = 32; off >= 1; off >>= 1) ps += __shfl_xor(ps, off, 64);
    float inv = 1.f / ps;

    // PV: lane = dim, broadcast p_l via readlane
    float oacc = 0.f;
#pragma unroll
    for (int wr2 = 0; wr2 < 7; ++wr2) {
#pragma unroll
      for (int wc2 = 0; wc2 < 7; ++wc2) {
        const int l2 = wr2 * 7 + wc2;
        float pl = __uint_as_float(__builtin_amdgcn_readlane(__float_as_uint(p), l2));
        int ldsr2 = (sj + wc2) * 7 + wr2;
        int g2 = (ldsr2 & 7) << 4;
        unsigned short vvu = *(const unsigned short*)((const char*)sV + ldsr2 * 128 + (d_off ^ g2));
        float vf = __uint_as_float((unsigned)vvu << 16);
        oacc = fmaf(pl, vf, oacc);
      }
    }
    aout[((size_t)(gb + iq * 32 + jq)) * 768 + h * 64 + lane] = f2bf(oacc * inv);
  }
}

// ---------------- launch ----------------
extern "C" void kernel_launch(void* const* d_in, const int* in_sizes, int n_in,
                              void* d_out, int out_size, void* d_ws, size_t ws_size,
                              hipStream_t stream) {
  const float* x      = (const float*)d_in[0];
  const float* qkv_w  = (const float*)d_in[1];
  const float* qkv_b  = (const float*)d_in[2];
  const float* proj_w = (const float*)d_in[3];
  const float* proj_b = (const float*)d_in[4];
  char* ws = (char*)d_ws;

  unsigned short* xb    = (unsigned short*)(ws);                 // 4096*768 bf16   (6,291,456 B)
  unsigned short* wqkv  = (unsigned short*)(ws + 6291456);       // 2304*768 bf16   (3,538,944 B)
  unsigned short* wproj = (unsigned short*)(ws + 9830400);       // 768*768 bf16    (1,179,648 B)
  unsigned short* qkvt  = (unsigned short*)(ws + 11010048);      // 3*12*4096*64    (18,874,368 B)
  unsigned short* attnb = (unsigned short*)(ws + 29884416);      // 4096*768 bf16   (6,291,456 B)
  float* out = (float*)d_out;

  cvt_kernel<<<5376, 256, 0, stream>>>(x, qkv_w, proj_w, xb, wqkv, wproj);
  gemm_bt<0><<<dim3(18, 32), 256, 0, stream>>>(xb, wqkv, qkv_b, qkvt, nullptr, 4096, 2304, 768);
  natten_kernel<<<dim3(12, 32, 4), 256, 0, stream>>>(qkvt, attnb);
  gemm_bt<1><<<dim3(6, 32), 256, 0, stream>>>(attnb, wproj, proj_b, nullptr, out, 4096, 768, 768);
}

// Round 2
// 155.495 us; speedup vs baseline: 1.2762x; 1.2762x over previous
//
#include <hip/hip_runtime.h>

// B=4, HG=WG=32 -> 1024 tokens/batch, 4096 total; D=768, NH=12, HD=64, K=7 (49 neighbors)

typedef __bf16 bf16x8 __attribute__((ext_vector_type(8)));
typedef short s16x4 __attribute__((ext_vector_type(4)));
typedef float f32x4 __attribute__((ext_vector_type(4)));

__device__ __forceinline__ unsigned short f2bf(float f) {
  unsigned u = __float_as_uint(f);
  u += 0x7fffu + ((u >> 16) & 1u);   // RNE
  return (unsigned short)(u >> 16);
}

template <typename T>
__device__ __forceinline__ void gld_lds16(const T* g, T* l) {
  __builtin_amdgcn_global_load_lds((const __attribute__((address_space(1))) void*)g,
                                   (__attribute__((address_space(3))) void*)l, 16, 0, 0);
}

// ---------------- fp32 -> bf16 conversion of x, qkv_w, proj_w ----------------
__global__ void cvt_kernel(const float* __restrict__ x, const float* __restrict__ w1,
                           const float* __restrict__ w2, unsigned short* __restrict__ xo,
                           unsigned short* __restrict__ w1o, unsigned short* __restrict__ w2o) {
  const int n1 = 4096 * 768 / 4;
  const int n2 = 2304 * 768 / 4;
  const int n3 = 768 * 768 / 4;
  int i = blockIdx.x * 256 + threadIdx.x;
  float4 v;
  unsigned short* dst;
  int o;
  if (i < n1) {
    o = i; v = ((const float4*)x)[o]; dst = xo;
  } else if (i < n1 + n2) {
    o = i - n1; v = ((const float4*)w1)[o]; dst = w1o;
  } else if (i < n1 + n2 + n3) {
    o = i - n1 - n2; v = ((const float4*)w2)[o]; dst = w2o;
  } else {
    return;
  }
  ushort4 r;
  r.x = f2bf(v.x); r.y = f2bf(v.y); r.z = f2bf(v.z); r.w = f2bf(v.w);
  ((ushort4*)dst)[o] = r;
}

// ---------------- bf16 GEMM, C = A * B^T + bias ----------------
// MODE 0 (qkv): Q cols scaled by 0.125*log2(e), written token-major [h][4096][64];
//               K written token-major; V written TRANSPOSED vt[h][64][4096].
// MODE 1 (proj): fp32 out, row-major.
template <int MODE>
__global__ __launch_bounds__(256) void gemm_bt(const unsigned short* __restrict__ A,
                                               const unsigned short* __restrict__ Bm,
                                               const float* __restrict__ bias,
                                               unsigned short* __restrict__ obf,
                                               unsigned short* __restrict__ vtout,
                                               float* __restrict__ of32,
                                               int M, int N, int Kd) {
  __shared__ __align__(16) unsigned short sA[128 * 32];
  __shared__ __align__(16) unsigned short sB[128 * 32];
  const int tid = threadIdx.x;
  const int lane = tid & 63;
  const int wv = tid >> 6;
  const int m0 = blockIdx.y * 128, n0 = blockIdx.x * 128;
  const int wrow = (wv >> 1) * 64, wcol = (wv & 1) * 64;
  const int lr = lane & 15, lq = lane >> 4;

  f32x4 acc[4][4] = {};

  const unsigned short* gA = A + (size_t)(m0 + (tid >> 2)) * Kd + (tid & 3) * 8;
  const unsigned short* gB = Bm + (size_t)(n0 + (tid >> 2)) * Kd + (tid & 3) * 8;

  for (int k0 = 0; k0 < Kd; k0 += 32) {
    gld_lds16(gA + k0, sA + tid * 8);
    gld_lds16(gA + (size_t)64 * Kd + k0, sA + 2048 + tid * 8);
    gld_lds16(gB + k0, sB + tid * 8);
    gld_lds16(gB + (size_t)64 * Kd + k0, sB + 2048 + tid * 8);
    __syncthreads();

    bf16x8 af[4], bfr[4];
#pragma unroll
    for (int t = 0; t < 4; ++t) {
      af[t] = *(const bf16x8*)(sA + (wrow + t * 16 + lr) * 32 + lq * 8);
      bfr[t] = *(const bf16x8*)(sB + (wcol + t * 16 + lr) * 32 + lq * 8);
    }
#pragma unroll
    for (int im = 0; im < 4; ++im)
#pragma unroll
      for (int in = 0; in < 4; ++in)
        acc[im][in] = __builtin_amdgcn_mfma_f32_16x16x32_bf16(af[im], bfr[in], acc[im][in], 0, 0, 0);
    __syncthreads();
  }

  if (MODE == 0) {
    const int sidx = n0 / 768;  // block-uniform (768 % 128 == 0)
    if (sidx == 2) {
      // V -> transposed vt[(hh*64+dd)*4096 + token]
#pragma unroll
      for (int im = 0; im < 4; ++im) {
#pragma unroll
        for (int in = 0; in < 4; ++in) {
          int gn = n0 + wcol + in * 16 + lr;
          int rem = gn - 1536;
          int hh = rem >> 6, dd = gn & 63;
          float bsv = bias[gn];
          int gm0 = m0 + wrow + im * 16 + lq * 4;
          ushort4 pk;
          pk.x = f2bf(acc[im][in][0] + bsv);
          pk.y = f2bf(acc[im][in][1] + bsv);
          pk.z = f2bf(acc[im][in][2] + bsv);
          pk.w = f2bf(acc[im][in][3] + bsv);
          *(ushort4*)(vtout + (size_t)(hh * 64 + dd) * 4096 + gm0) = pk;
        }
      }
    } else {
      const float scale = (sidx == 0) ? 0.18033688f : 1.0f;  // 0.125 * log2(e) for Q
#pragma unroll
      for (int im = 0; im < 4; ++im) {
#pragma unroll
        for (int in = 0; in < 4; ++in) {
          int gn = n0 + wcol + in * 16 + lr;
          int rem = gn - sidx * 768;
          int hh = rem >> 6, dd = gn & 63;
          float bsv = bias[gn];
#pragma unroll
          for (int r = 0; r < 4; ++r) {
            int gm = m0 + wrow + im * 16 + lq * 4 + r;
            float val = (acc[im][in][r] + bsv) * scale;
            obf[((size_t)(sidx * 12 + hh) * 4096 + gm) * 64 + dd] = f2bf(val);
          }
        }
      }
    }
  } else {
#pragma unroll
    for (int im = 0; im < 4; ++im) {
#pragma unroll
      for (int in = 0; in < 4; ++in) {
        int gn = n0 + wcol + in * 16 + lr;
        float bsv = bias[gn];
#pragma unroll
        for (int r = 0; r < 4; ++r) {
          int gm = m0 + wrow + im * 16 + lq * 4 + r;
          of32[(size_t)gm * N + gn] = acc[im][in][r] + bsv;
        }
      }
    }
  }
}

// ---------------- neighborhood attention (MFMA) ----------------
// Block = (head, query-row-pair, batch): 64 queries, stages 8 KV grid rows (256 tok).
// S^T = K·Q^T via mfma_16x16x16_bf16: C-layout (col=lane&15=q, row=lg*4+reg=t) is
// EXACTLY the A-operand layout of PV (m=lane&15, k=lg*4+j) -> P stays in registers.
// Dense 224-token scores with -inf column mask; exp2-softmax (log2e folded into Q).
__global__ __launch_bounds__(256, 2) void natten_kernel(const unsigned short* __restrict__ qkvt,
                                                        unsigned short* __restrict__ aout) {
  __shared__ __align__(16) unsigned short sQ[64 * 64];    //  8 KB
  __shared__ __align__(16) unsigned short sK[256 * 64];   // 32 KB
  __shared__ __align__(16) unsigned short sVt[64 * 256];  // 32 KB
  const int h = blockIdx.x, ip = blockIdx.y, b = blockIdx.z;
  const int i0 = ip * 2;
  const int tid = threadIdx.x, lane = tid & 63, wv = tid >> 6;
  const int lg = lane >> 4, lm = lane & 15;
  int si0 = i0 - 3; si0 = si0 < 0 ? 0 : si0; if (si0 > 25) si0 = 25;
  const int gb = b * 1024;
  const unsigned short* Qg = qkvt + ((size_t)h * 4096 + gb + i0 * 32) * 64;
  const unsigned short* Kg = qkvt + ((size_t)(12 + h) * 4096 + gb) * 64;
  const unsigned short* Vg = qkvt + (size_t)24 * 4096 * 64 + (size_t)h * 64 * 4096 + gb;

  // ---- staging (16B global loads, two 8B LDS writes w/ 4-bit XOR chunk swizzle) ----
#pragma unroll
  for (int it = 0; it < 2; ++it) {  // Q: 64 q x 64 d
    int f = it * 256 + tid;
    int q = f >> 3, c16 = f & 7;
    uint4 v = *(const uint4*)(Qg + q * 64 + c16 * 8);
    int s = q & 15;
    *(uint2*)(sQ + q * 64 + ((((c16 << 1)) ^ s) << 2)) = make_uint2(v.x, v.y);
    *(uint2*)(sQ + q * 64 + ((((c16 << 1) | 1) ^ s) << 2)) = make_uint2(v.z, v.w);
  }
#pragma unroll
  for (int it = 0; it < 8; ++it) {  // K: 256 tok x 64 d
    int f = it * 256 + tid;
    int t = f >> 3, c16 = f & 7;
    int wr = t >> 5, c = t & 31;
    int row = si0 + wr; if (row > 31) row = 31;
    uint4 v = *(const uint4*)(Kg + (row * 32 + c) * 64 + c16 * 8);
    int s = t & 15;
    *(uint2*)(sK + t * 64 + ((((c16 << 1)) ^ s) << 2)) = make_uint2(v.x, v.y);
    *(uint2*)(sK + t * 64 + ((((c16 << 1) | 1) ^ s) << 2)) = make_uint2(v.z, v.w);
  }
#pragma unroll
  for (int it = 0; it < 8; ++it) {  // Vt: 64 d x 256 tok
    int f = it * 256 + tid;
    int d = f >> 5, tc16 = f & 31;
    int wr = tc16 >> 2;
    int row = si0 + wr; if (row > 31) row = 31;
    uint4 v = *(const uint4*)(Vg + (size_t)d * 4096 + row * 32 + (tc16 & 3) * 8);
    int s = d & 15;
    *(uint2*)(sVt + d * 256 + ((((tc16 << 1)) ^ s) << 2)) = make_uint2(v.x, v.y);
    *(uint2*)(sVt + d * 256 + ((((tc16 << 1) | 1) ^ s) << 2)) = make_uint2(v.z, v.w);
  }
  __syncthreads();

  const int row_sel = wv >> 1;
  const int jhalf = wv & 1;
  const int i = i0 + row_sel;
  int si_w = i - 3; si_w = si_w < 0 ? 0 : si_w; if (si_w > 25) si_w = 25;
  const int toff = (si_w - si0) * 32;
  const int j = jhalf * 16 + lm;
  int sj = j - 3; sj = sj < 0 ? 0 : sj; if (sj > 25) sj = 25;

  // column mask: token col c depends only on (tile parity, lg, reg)
  float madd[2][4];
#pragma unroll
  for (int p = 0; p < 2; ++p)
#pragma unroll
    for (int r = 0; r < 4; ++r) {
      int c = p * 16 + lg * 4 + r;
      madd[p][r] = (c >= sj && c <= sj + 6) ? 0.f : -1e30f;
    }

  // Q B-fragments (held in regs, reused across all token tiles)
  s16x4 qf[4];
  const int qrow = row_sel * 32 + j;
#pragma unroll
  for (int ks = 0; ks < 4; ++ks)
    qf[ks] = *(const s16x4*)(sQ + qrow * 64 + ((((ks << 2) + lg) ^ (qrow & 15)) << 2));

  // S^T = K · Q^T
  f32x4 accS[14];
#pragma unroll
  for (int tt = 0; tt < 14; ++tt) {
    f32x4 a = {0.f, 0.f, 0.f, 0.f};
    const int trow = toff + tt * 16 + lm;
    const unsigned short* kr = sK + trow * 64;
    const int sw = trow & 15;
#pragma unroll
    for (int ks = 0; ks < 4; ++ks) {
      s16x4 kf = *(const s16x4*)(kr + ((((ks << 2) + lg) ^ sw) << 2));
      a = __builtin_amdgcn_mfma_f32_16x16x16bf16_1k(kf, qf[ks], a, 0, 0, 0);
    }
    accS[tt] = a;
  }

  // masked softmax (base-2; scale pre-folded into Q)
  float mx = -3e38f;
#pragma unroll
  for (int tt = 0; tt < 14; ++tt)
#pragma unroll
    for (int r = 0; r < 4; ++r) {
      float v = accS[tt][r] + madd[tt & 1][r];
      accS[tt][r] = v;
      mx = fmaxf(mx, v);
    }
  mx = fmaxf(mx, __shfl_xor(mx, 16, 64));
  mx = fmaxf(mx, __shfl_xor(mx, 32, 64));
  float sum = 0.f;
#pragma unroll
  for (int tt = 0; tt < 14; ++tt)
#pragma unroll
    for (int r = 0; r < 4; ++r) {
      float p = exp2f(accS[tt][r] - mx);
      accS[tt][r] = p;
      sum += p;
    }
  sum += __shfl_xor(sum, 16, 64);
  sum += __shfl_xor(sum, 32, 64);
  const float inv = 1.f / sum;

  // P fp32 -> bf16 A-fragments (register-direct, no LDS round-trip)
  s16x4 pf[14];
#pragma unroll
  for (int tt = 0; tt < 14; ++tt) {
    union { unsigned u[2]; s16x4 v; } pk;
    pk.u[0] = ((unsigned)f2bf(accS[tt][1]) << 16) | f2bf(accS[tt][0]);
    pk.u[1] = ((unsigned)f2bf(accS[tt][3]) << 16) | f2bf(accS[tt][2]);
    pf[tt] = pk.v;
  }

  // O = P · V
  f32x4 accO[4] = {};
  const int choff = toff >> 2;
#pragma unroll
  for (int tt = 0; tt < 14; ++tt) {
    const int c8 = choff + tt * 4 + lg;
#pragma unroll
    for (int nt = 0; nt < 4; ++nt) {
      const int d = nt * 16 + lm;
      s16x4 vf = *(const s16x4*)(sVt + d * 256 + ((c8 ^ (d & 15)) << 2));
      accO[nt] = __builtin_amdgcn_mfma_f32_16x16x16bf16_1k(pf[tt], vf, accO[nt], 0, 0, 0);
    }
  }

  // 1/sum per output row (O C-layout row = q = lg*4+reg)
  float invr[4];
#pragma unroll
  for (int r = 0; r < 4; ++r) invr[r] = __shfl(inv, lg * 4 + r, 64);

  const int tokbase = gb + i * 32 + jhalf * 16;
#pragma unroll
  for (int nt = 0; nt < 4; ++nt)
#pragma unroll
    for (int r = 0; r < 4; ++r) {
      int tok = tokbase + lg * 4 + r;
      aout[(size_t)tok * 768 + h * 64 + nt * 16 + lm] = f2bf(accO[nt][r] * invr[r]);
    }
}

// ---------------- launch ----------------
extern "C" void kernel_launch(void* const* d_in, const int* in_sizes, int n_in,
                              void* d_out, int out_size, void* d_ws, size_t ws_size,
                              hipStream_t stream) {
  const float* x      = (const float*)d_in[0];
  const float* qkv_w  = (const float*)d_in[1];
  const float* qkv_b  = (const float*)d_in[2];
  const float* proj_w = (const float*)d_in[3];
  const float* proj_b = (const float*)d_in[4];
  char* ws = (char*)d_ws;

  unsigned short* xb    = (unsigned short*)(ws);                 // 4096*768 bf16
  unsigned short* wqkv  = (unsigned short*)(ws + 6291456);       // 2304*768 bf16
  unsigned short* wproj = (unsigned short*)(ws + 9830400);       // 768*768 bf16
  unsigned short* qkvt  = (unsigned short*)(ws + 11010048);      // Q,K token-major + Vt
  unsigned short* attnb = (unsigned short*)(ws + 29884416);      // 4096*768 bf16
  unsigned short* vt    = qkvt + (size_t)24 * 4096 * 64;         // V transposed [12][64][4096]
  float* out = (float*)d_out;

  cvt_kernel<<<5376, 256, 0, stream>>>(x, qkv_w, proj_w, xb, wqkv, wproj);
  gemm_bt<0><<<dim3(18, 32), 256, 0, stream>>>(xb, wqkv, qkv_b, qkvt, vt, nullptr, 4096, 2304, 768);
  natten_kernel<<<dim3(12, 16, 4), 256, 0, stream>>>(qkvt, attnb);
  gemm_bt<1><<<dim3(6, 32), 256, 0, stream>>>(attnb, wproj, proj_b, nullptr, nullptr, out, 4096, 768, 768);
}